// Round 4
// baseline (93.850 us; speedup 1.0000x reference)
//
#include <hip/hip_runtime.h>

// B=256, IN_F=512, K_INT=75, OUT_F=64
// ws: Mt[o][k][b] fp32 = 64*75*256*4 = 4,915,200 B

// ---------------- GEMM: Mt[o][kc][b] = sum_f x[b][f] * T[f][kc][o] ----------------
// Block: (32-b tile, one kc). 256 thr = 16 b-pairs x 16 o-quads. Thread: 4 o x 2 b.
// x staged once in LDS (even/odd-b arrays, pad 516 -> 2-way-free b128 reads).
// T streamed from L2 (4 distinct 16B addrs per wave-load -> merged), prefetch depth 1.
// Zero __syncthreads in the main loop.
__global__ __launch_bounds__(256) void md_gemm(const float* __restrict__ x,
                                               const float* __restrict__ T,
                                               float* __restrict__ Mt) {
  const int btile = blockIdx.x << 5;   // 0..224
  const int kc = blockIdx.y;           // 0..74
  const int tid = threadIdx.x;
  const int bg = tid & 15;             // b = btile + 2*bg + e
  const int oq = tid >> 4;             // o = 4*oq + d

  __shared__ alignas(16) float xsE[16][516];  // b-local even rows
  __shared__ alignas(16) float xsO[16][516];  // b-local odd rows

  // stage x[btile .. btile+32) : 4096 float4, coalesced global, 2-way LDS writes
  const float4* x4 = reinterpret_cast<const float4*>(x);
#pragma unroll
  for (int h = 0; h < 16; ++h) {
    const int idx = (h << 8) + tid;    // 0..4095
    const int r = idx >> 7;            // 0..31 (wave-uniform)
    const int c = idx & 127;           // float4 col
    const float4 v = x4[(btile + r) * 128 + c];
    float* dst = (r & 1) ? &xsO[r >> 1][c << 2] : &xsE[r >> 1][c << 2];
    *reinterpret_cast<float4*>(dst) = v;
  }
  __syncthreads();

  float acc[4][2];                     // [d=o][e=b]
#pragma unroll
  for (int d = 0; d < 4; ++d) { acc[d][0] = 0.0f; acc[d][1] = 0.0f; }

  // T quads: dword index f*4800 + kc*64 + 4*oq  ->  quad index f*1200 + kc*16 + oq
  const float4* Tp = reinterpret_cast<const float4*>(T) + kc * 16 + oq;

  float4 t[4], tn[4];
#pragma unroll
  for (int q = 0; q < 4; ++q) t[q] = Tp[q * 1200];

  for (int it = 0; it < 128; ++it) {
    if (it < 127) {
      const float4* Tnext = Tp + (4 * (it + 1)) * 1200;
#pragma unroll
      for (int q = 0; q < 4; ++q) tn[q] = Tnext[q * 1200];
    }
    const float4 xa = *reinterpret_cast<const float4*>(&xsE[bg][it << 2]);
    const float4 xb = *reinterpret_cast<const float4*>(&xsO[bg][it << 2]);
    const float xaq[4] = {xa.x, xa.y, xa.z, xa.w};
    const float xbq[4] = {xb.x, xb.y, xb.z, xb.w};
#pragma unroll
    for (int q = 0; q < 4; ++q) {
      acc[0][0] += t[q].x * xaq[q];  acc[0][1] += t[q].x * xbq[q];
      acc[1][0] += t[q].y * xaq[q];  acc[1][1] += t[q].y * xbq[q];
      acc[2][0] += t[q].z * xaq[q];  acc[2][1] += t[q].z * xbq[q];
      acc[3][0] += t[q].w * xaq[q];  acc[3][1] += t[q].w * xbq[q];
    }
#pragma unroll
    for (int q = 0; q < 4; ++q) t[q] = tn[q];
  }

  // store: float2 per o-row, lanes cover 32 consecutive b -> 128 B coalesced
#pragma unroll
  for (int d = 0; d < 4; ++d) {
    const int o = (oq << 2) + d;
    float2 v = make_float2(acc[d][0], acc[d][1]);
    *reinterpret_cast<float2*>(Mt + o * 19200 + kc * 256 + btile + (bg << 1)) = v;
  }
}

// ---------------- pairwise L1 + exp + row-sum ----------------
// Block: (o, 32-i chunk). k split into halves of 38/37 so LDS=38.9KB -> 4 blocks/CU.
// Thread (io,jg): 2 i's x 16 j's. Per k: 2 bcast b32 + 4 bcast b128 + 64 VALU.
__global__ __launch_bounds__(256) void md_pair(const float* __restrict__ Mt,
                                               float* __restrict__ out) {
  const int o = blockIdx.x;            // 0..63
  const int ibase = blockIdx.y << 5;   // 32 i per block
  const int tid = threadIdx.x;
  const int io = tid & 15;             // i = ibase + 2*io + e
  const int jg = tid >> 4;             // j in [16*jg, 16*jg+16)

  __shared__ alignas(16) float Ms[38 * 256];   // 38,912 B

  float d0[16], d1[16];
#pragma unroll
  for (int q = 0; q < 16; ++q) { d0[q] = 0.0f; d1[q] = 0.0f; }

  const int i0 = ibase + (io << 1);

  for (int kh = 0; kh < 2; ++kh) {
    const int nk = kh ? 37 : 38;
    // stage half: contiguous copy (coalesced global, conflict-free LDS)
    {
      const float4* src4 = reinterpret_cast<const float4*>(Mt + o * 19200 + kh * (38 * 256));
      float4* dst4 = reinterpret_cast<float4*>(Ms);
      const int n4 = nk << 6;          // nk*256/4
      for (int idx = tid; idx < n4; idx += 256) dst4[idx] = src4[idx];
    }
    __syncthreads();

    for (int k = 0; k < nk; ++k) {
      const float* row = Ms + (k << 8);
      const float mi0 = row[i0];                       // conflict-free (stride-2 banks)
      const float mi1 = row[i0 + 1];
      const float4* row4 = reinterpret_cast<const float4*>(row) + (jg << 2);
#pragma unroll
      for (int q = 0; q < 4; ++q) {
        const float4 v = row4[q];                      // 4 distinct addrs/wave: bcast
        d0[4 * q + 0] += __builtin_fabsf(v.x - mi0);
        d0[4 * q + 1] += __builtin_fabsf(v.y - mi0);
        d0[4 * q + 2] += __builtin_fabsf(v.z - mi0);
        d0[4 * q + 3] += __builtin_fabsf(v.w - mi0);
        d1[4 * q + 0] += __builtin_fabsf(v.x - mi1);
        d1[4 * q + 1] += __builtin_fabsf(v.y - mi1);
        d1[4 * q + 2] += __builtin_fabsf(v.z - mi1);
        d1[4 * q + 3] += __builtin_fabsf(v.w - mi1);
      }
    }
    __syncthreads();   // all reads done before refill / reuse
  }

  float s0 = 0.0f, s1 = 0.0f;
#pragma unroll
  for (int q = 0; q < 16; ++q) {
    s0 += __expf(-d0[q]);              // j==i term: exp(0)=1 cancels the -1
    s1 += __expf(-d1[q]);
  }

  // reduce 16 jg-partials per i
  float* red = Ms;                     // rows stride 17: conflict-free
  red[((io << 1) + 0) * 17 + jg] = s0;
  red[((io << 1) + 1) * 17 + jg] = s1;
  __syncthreads();
  if (tid < 32) {
    float s = 0.0f;
#pragma unroll
    for (int g = 0; g < 16; ++g) s += red[tid * 17 + g];
    out[(ibase + tid) * 64 + o] = s - 1.0f;
  }
}

extern "C" void kernel_launch(void* const* d_in, const int* in_sizes, int n_in,
                              void* d_out, int out_size, void* d_ws, size_t ws_size,
                              hipStream_t stream) {
  const float* x = (const float*)d_in[0];   // [256,512]
  const float* T = (const float*)d_in[1];   // [512,75,64]
  float* out = (float*)d_out;               // [256,64]
  float* Mt = (float*)d_ws;                 // [64][75][256]

  md_gemm<<<dim3(8, 75), 256, 0, stream>>>(x, T, Mt);
  md_pair<<<dim3(64, 8), 256, 0, stream>>>(Mt, out);
}

// Round 5
// 57.733 us; speedup vs baseline: 1.6256x; 1.6256x over previous
//
#include <hip/hip_runtime.h>

// B=256, IN_F=512, K_INT=75, OUT_F=64
// ws: Mt[o][k][b] fp32   @ 0        (4,915,200 B)
//     Tb[k*64+o][f] bf16 @ 4915200  (4,915,200 B)
//     xb[b][f]      bf16 @ 9830400  (  262,144 B)

typedef __attribute__((ext_vector_type(8))) short bf16x8;
typedef __attribute__((ext_vector_type(4))) float f32x4;
typedef unsigned short ushort_t;
typedef unsigned int uint_t;

__device__ inline ushort_t f2bf(float f) {           // RNE float->bf16 bits
  uint_t u = __float_as_uint(f);
  return (ushort_t)((u + 0x7FFFu + ((u >> 16) & 1u)) >> 16);
}

// ---------- x[256][512] fp32 -> xb bf16 (row-major) ----------
__global__ __launch_bounds__(256) void cvt_x(const float* __restrict__ x,
                                             ushort_t* __restrict__ xb) {
  const int i = blockIdx.x * 256 + threadIdx.x;      // 16384 threads x 8 elems
  const float4* x4 = reinterpret_cast<const float4*>(x);
  const float4 v0 = x4[i * 2], v1 = x4[i * 2 + 1];
  uint4 o;
  o.x = (uint_t)f2bf(v0.x) | ((uint_t)f2bf(v0.y) << 16);
  o.y = (uint_t)f2bf(v0.z) | ((uint_t)f2bf(v0.w) << 16);
  o.z = (uint_t)f2bf(v1.x) | ((uint_t)f2bf(v1.y) << 16);
  o.w = (uint_t)f2bf(v1.z) | ((uint_t)f2bf(v1.w) << 16);
  *reinterpret_cast<uint4*>(xb + i * 8) = o;
}

// ---------- T[f][k][o] fp32 -> Tb[k*64+o][f] bf16 (LDS 64x64 transpose) ----------
__global__ __launch_bounds__(256) void cvt_T(const float* __restrict__ T,
                                             ushort_t* __restrict__ Tb) {
  const int f0 = blockIdx.x << 6;    // f-tile 0..7
  const int k = blockIdx.y;          // 0..74
  const int tid = threadIdx.x;
  __shared__ float tile[64][65];     // [f_local][o], pad 65 breaks read conflicts

  const float4* T4 = reinterpret_cast<const float4*>(T);
  const int r = tid >> 2;            // f row 0..63
  const int c = tid & 3;
#pragma unroll
  for (int h = 0; h < 4; ++h) {
    const int q = c + (h << 2);                        // o-quad 0..15
    const float4 v = T4[(f0 + r) * 1200 + k * 16 + q]; // coalesced-ish row reads
    tile[r][(q << 2) + 0] = v.x;
    tile[r][(q << 2) + 1] = v.y;
    tile[r][(q << 2) + 2] = v.z;
    tile[r][(q << 2) + 3] = v.w;
  }
  __syncthreads();

  const int w = tid >> 2;            // o row 0..63
  ushort_t us[16];
#pragma unroll
  for (int j = 0; j < 16; ++j) us[j] = f2bf(tile[(c << 4) + j][w]);
  uint4 p0, p1;
  p0.x = (uint_t)us[0] | ((uint_t)us[1] << 16);
  p0.y = (uint_t)us[2] | ((uint_t)us[3] << 16);
  p0.z = (uint_t)us[4] | ((uint_t)us[5] << 16);
  p0.w = (uint_t)us[6] | ((uint_t)us[7] << 16);
  p1.x = (uint_t)us[8] | ((uint_t)us[9] << 16);
  p1.y = (uint_t)us[10] | ((uint_t)us[11] << 16);
  p1.z = (uint_t)us[12] | ((uint_t)us[13] << 16);
  p1.w = (uint_t)us[14] | ((uint_t)us[15] << 16);
  uint4* dst = reinterpret_cast<uint4*>(Tb + ((k << 6) + w) * 512 + f0 + (c << 4));
  dst[0] = p0;
  dst[1] = p1;
}

// ---------- MFMA GEMM: Mt[o][k][b] = sum_f Tb[k*64+o][f] * xb[b][f] ----------
// Grid (75 n-tiles of 64, 4 b-tiles of 64). Block 256 thr = 4 waves (2n x 2b).
// Wave tile 32n x 32b = 4 MFMA 16x16 accs; K-loop 16 steps of 32.
__global__ __launch_bounds__(256) void md_gemm_mfma(const ushort_t* __restrict__ Tb,
                                                    const ushort_t* __restrict__ xb,
                                                    float* __restrict__ Mt) {
  const int tid = threadIdx.x;
  const int l = tid & 63, w = tid >> 6;
  const int n0 = (blockIdx.x << 6) + ((w >> 1) << 5);
  const int b0 = (blockIdx.y << 6) + ((w & 1) << 5);
  const int lr = l & 15;             // A-row / B-col / D-col within 16-tile
  const int ko = (l >> 4) << 3;      // k-offset within 32 (8 contiguous)

  const ushort_t* pa0 = Tb + (n0 + lr) * 512 + ko;
  const ushort_t* pa1 = pa0 + 16 * 512;
  const ushort_t* pb0 = xb + (b0 + lr) * 512 + ko;
  const ushort_t* pb1 = pb0 + 16 * 512;

  f32x4 d00 = {0.f, 0.f, 0.f, 0.f}, d01 = d00, d10 = d00, d11 = d00;

#pragma unroll 4
  for (int kk = 0; kk < 16; ++kk) {
    const int off = kk << 5;
    const bf16x8 a0 = *reinterpret_cast<const bf16x8*>(pa0 + off);
    const bf16x8 a1 = *reinterpret_cast<const bf16x8*>(pa1 + off);
    const bf16x8 f0 = *reinterpret_cast<const bf16x8*>(pb0 + off);
    const bf16x8 f1 = *reinterpret_cast<const bf16x8*>(pb1 + off);
    d00 = __builtin_amdgcn_mfma_f32_16x16x32_bf16(a0, f0, d00, 0, 0, 0);
    d01 = __builtin_amdgcn_mfma_f32_16x16x32_bf16(a0, f1, d01, 0, 0, 0);
    d10 = __builtin_amdgcn_mfma_f32_16x16x32_bf16(a1, f0, d10, 0, 0, 0);
    d11 = __builtin_amdgcn_mfma_f32_16x16x32_bf16(a1, f1, d11, 0, 0, 0);
  }

  // D: col = lane&15, row = (lane>>4)*4 + reg (m89-verified). n = k*64+o.
#pragma unroll
  for (int r = 0; r < 4; ++r) {
    const int row = ((l >> 4) << 2) + r;
    {
      const int n = n0 + row;
      float* base = Mt + (n & 63) * 19200 + (n >> 6) * 256;
      base[b0 + lr] = d00[r];
      base[b0 + 16 + lr] = d01[r];
    }
    {
      const int n = n0 + 16 + row;
      float* base = Mt + (n & 63) * 19200 + (n >> 6) * 256;
      base[b0 + lr] = d10[r];
      base[b0 + 16 + lr] = d11[r];
    }
  }
}

// ---------------- pairwise L1 + exp + row-sum (unchanged from R4) ----------------
__global__ __launch_bounds__(256) void md_pair(const float* __restrict__ Mt,
                                               float* __restrict__ out) {
  const int o = blockIdx.x;            // 0..63
  const int ibase = blockIdx.y << 5;   // 32 i per block
  const int tid = threadIdx.x;
  const int io = tid & 15;             // i = ibase + 2*io + e
  const int jg = tid >> 4;             // j in [16*jg, 16*jg+16)

  __shared__ alignas(16) float Ms[38 * 256];   // 38,912 B

  float d0[16], d1[16];
#pragma unroll
  for (int q = 0; q < 16; ++q) { d0[q] = 0.0f; d1[q] = 0.0f; }

  const int i0 = ibase + (io << 1);

  for (int kh = 0; kh < 2; ++kh) {
    const int nk = kh ? 37 : 38;
    {
      const float4* src4 = reinterpret_cast<const float4*>(Mt + o * 19200 + kh * (38 * 256));
      float4* dst4 = reinterpret_cast<float4*>(Ms);
      const int n4 = nk << 6;
      for (int idx = tid; idx < n4; idx += 256) dst4[idx] = src4[idx];
    }
    __syncthreads();

    for (int k = 0; k < nk; ++k) {
      const float* row = Ms + (k << 8);
      const float mi0 = row[i0];
      const float mi1 = row[i0 + 1];
      const float4* row4 = reinterpret_cast<const float4*>(row) + (jg << 2);
#pragma unroll
      for (int q = 0; q < 4; ++q) {
        const float4 v = row4[q];
        d0[4 * q + 0] += __builtin_fabsf(v.x - mi0);
        d0[4 * q + 1] += __builtin_fabsf(v.y - mi0);
        d0[4 * q + 2] += __builtin_fabsf(v.z - mi0);
        d0[4 * q + 3] += __builtin_fabsf(v.w - mi0);
        d1[4 * q + 0] += __builtin_fabsf(v.x - mi1);
        d1[4 * q + 1] += __builtin_fabsf(v.y - mi1);
        d1[4 * q + 2] += __builtin_fabsf(v.z - mi1);
        d1[4 * q + 3] += __builtin_fabsf(v.w - mi1);
      }
    }
    __syncthreads();
  }

  float s0 = 0.0f, s1 = 0.0f;
#pragma unroll
  for (int q = 0; q < 16; ++q) {
    s0 += __expf(-d0[q]);              // j==i term: exp(0)=1 cancels the -1
    s1 += __expf(-d1[q]);
  }

  float* red = Ms;                     // rows stride 17: conflict-free
  red[((io << 1) + 0) * 17 + jg] = s0;
  red[((io << 1) + 1) * 17 + jg] = s1;
  __syncthreads();
  if (tid < 32) {
    float s = 0.0f;
#pragma unroll
    for (int g = 0; g < 16; ++g) s += red[tid * 17 + g];
    out[(ibase + tid) * 64 + o] = s - 1.0f;
  }
}

extern "C" void kernel_launch(void* const* d_in, const int* in_sizes, int n_in,
                              void* d_out, int out_size, void* d_ws, size_t ws_size,
                              hipStream_t stream) {
  const float* x = (const float*)d_in[0];   // [256,512]
  const float* T = (const float*)d_in[1];   // [512,75,64]
  float* out = (float*)d_out;               // [256,64]

  char* ws = (char*)d_ws;
  float* Mt = (float*)ws;                          // 4,915,200 B
  ushort_t* Tb = (ushort_t*)(ws + 4915200);        // 4,915,200 B
  ushort_t* xb = (ushort_t*)(ws + 9830400);        //   262,144 B

  cvt_x<<<64, 256, 0, stream>>>(x, xb);
  cvt_T<<<dim3(8, 75), 256, 0, stream>>>(T, Tb);
  md_gemm_mfma<<<dim3(75, 4), 256, 0, stream>>>(Tb, xb, Mt);
  md_pair<<<dim3(64, 8), 256, 0, stream>>>(Mt, out);
}